// Round 3
// baseline (194.161 us; speedup 1.0000x reference)
//
#include <hip/hip_runtime.h>

// ---------------------------------------------------------------------------
// TransitionModel: attn(32x32, head_dim=1) -> MLP(1152->1024->1024->1024) -> gumbel softmax
// B=8192, N=32, K=32, FLAT=1024, A=128, H=1024
// Strategy: bf16 MFMA for all matmuls (threshold 2e-2 permits), fp32 softmax math.
// ---------------------------------------------------------------------------

using bf16x8 = __attribute__((ext_vector_type(8))) short;  // 8 bf16 (4 VGPRs), per guide §3
using f32x4  = __attribute__((ext_vector_type(4))) float;

// fp32 -> bf16 RNE, pure bit math (finite inputs only)
__device__ __forceinline__ short f2bf(float x) {
  unsigned u = __builtin_bit_cast(unsigned, x);
  unsigned r = (u + 0x7fffu + ((u >> 16) & 1u)) >> 16;
  return (short)r;
}

__device__ __forceinline__ bf16x8 pack8(float4 a, float4 b) {
  bf16x8 r;
  r[0] = f2bf(a.x); r[1] = f2bf(a.y); r[2] = f2bf(a.z); r[3] = f2bf(a.w);
  r[4] = f2bf(b.x); r[5] = f2bf(b.y); r[6] = f2bf(b.z); r[7] = f2bf(b.w);
  return r;
}

// ---------------------------------------------------------------------------
// Kernel 0: f32 -> bf16 cast for the big fc weights (n divisible by 4)
// ---------------------------------------------------------------------------
__global__ __launch_bounds__(256) void cast_f2b(const float* __restrict__ src,
                                                short* __restrict__ dst, int n) {
  int i = (blockIdx.x * 256 + threadIdx.x) * 4;
  if (i >= n) return;
  float4 v = *(const float4*)(src + i);
  short4 o;
  o.x = f2bf(v.x); o.y = f2bf(v.y); o.z = f2bf(v.z); o.w = f2bf(v.w);
  *(short4*)(dst + i) = o;
}

// ---------------------------------------------------------------------------
// Kernel 1: per-batch attention + pack ba = [attn_belief(1024) | action(128)] bf16
// 1 block (256 thr, 4 waves) per batch.
//  - qkv = x @ in_proj_w^T + b via 12x mfma_16x16x32 (K=32 exact), f32 -> LDS
//  - softmax over j per (i,h): scores q_i*k_j tiny (W scale 0.02) -> no max-sub
//  - out proj via 4x mfma, epilogue writes bf16 ba
// ---------------------------------------------------------------------------
#define SQS 100  // sqkv row stride in floats (breaks 96-stride bank aliasing)

__global__ __launch_bounds__(256) void attn_kernel(
    const float* __restrict__ lat, const float* __restrict__ aemb,
    const float* __restrict__ ipw, const float* __restrict__ ipb,
    const float* __restrict__ opw, const float* __restrict__ opb,
    short* __restrict__ ba) {
  const int b = blockIdx.x;
  const int t = threadIdx.x;
  const int lane = t & 63;
  const int w = t >> 6;
  const int lr = lane & 15;   // fragment row/col index
  const int lg = lane >> 4;   // k-group 0..3
  const int k0 = lg * 8;

  __shared__ float sqkv[32 * SQS];            // qkv[i][j], f32
  __shared__ __align__(16) short so[32 * 32]; // o[i][h], bf16 (A-operand of out proj)

  // ---- phase 1: qkv via MFMA ----
  // A frags: x rows (bf16 cast inline). A[m=lr][k=k0+j] contiguous 8 floats.
  const float* xb = lat + b * 1024;
  bf16x8 af0, af1;
  {
    const float* p = xb + lr * 32 + k0;
    af0 = pack8(*(const float4*)p, *(const float4*)(p + 4));
    p += 16 * 32;
    af1 = pack8(*(const float4*)p, *(const float4*)(p + 4));
  }
  // ni (0..5) distribution over 4 waves: w0:{0,4} w1:{1,5} w2:{2} w3:{3}
  int nlist[2];
  const int ncnt = (w < 2) ? 2 : 1;
  nlist[0] = w; nlist[1] = w + 4;
  for (int qi = 0; qi < ncnt; ++qi) {
    const int ni = nlist[qi];
    const int j = ni * 16 + lr;                 // qkv column 0..95
    const float* p = ipw + j * 32 + k0;         // B[k][n] = ipw[n*32+k]
    bf16x8 bfr = pack8(*(const float4*)p, *(const float4*)(p + 4));
    const float bias = ipb[j];
    f32x4 acc0; acc0[0] = bias; acc0[1] = bias; acc0[2] = bias; acc0[3] = bias;
    f32x4 acc1 = acc0;
    acc0 = __builtin_amdgcn_mfma_f32_16x16x32_bf16(af0, bfr, acc0, 0, 0, 0);
    acc1 = __builtin_amdgcn_mfma_f32_16x16x32_bf16(af1, bfr, acc1, 0, 0, 0);
    // D: row=(lane>>4)*4+r, col=lane&15  (guide-verified layout)
#pragma unroll
    for (int r = 0; r < 4; ++r) {
      sqkv[(lg * 4 + r) * SQS + j] = acc0[r];
      sqkv[(16 + lg * 4 + r) * SQS + j] = acc1[r];
    }
  }
  __syncthreads();

  // ---- phase 2: softmax-weighted V. thread -> (h = t&31, rows ig*4..ig*4+3) ----
  {
    const int h = t & 31;
    const int ig = t >> 5;
    float qv[4], num[4], den[4];
#pragma unroll
    for (int c = 0; c < 4; ++c) {
      qv[c] = sqkv[(ig * 4 + c) * SQS + h];
      num[c] = 0.f; den[c] = 0.f;
    }
#pragma unroll 4
    for (int j = 0; j < 32; ++j) {
      const float kv = sqkv[j * SQS + 32 + h];  // lanes h consecutive: conflict-free
      const float vv = sqkv[j * SQS + 64 + h];
#pragma unroll
      for (int c = 0; c < 4; ++c) {
        const float e = __expf(qv[c] * kv);     // |q*k| << 1: no max-sub needed
        den[c] += e;
        num[c] = fmaf(e, vv, num[c]);
      }
    }
#pragma unroll
    for (int c = 0; c < 4; ++c)
      so[(ig * 4 + c) * 32 + h] = f2bf(num[c] / den[c]);
  }
  __syncthreads();

  // ---- phase 3: out proj (32x32x32), 1 mfma per wave ----
  {
    const int mi = w >> 1, ni = w & 1;
    bf16x8 afr = *(const bf16x8*)&so[(mi * 16 + lr) * 32 + k0];
    const int c = ni * 16 + lr;
    const float* p = opw + c * 32 + k0;
    bf16x8 bfr = pack8(*(const float4*)p, *(const float4*)(p + 4));
    const float bias = opb[c];
    f32x4 acc; acc[0] = bias; acc[1] = bias; acc[2] = bias; acc[3] = bias;
    acc = __builtin_amdgcn_mfma_f32_16x16x32_bf16(afr, bfr, acc, 0, 0, 0);
    short* bab = ba + (size_t)b * 1152;
#pragma unroll
    for (int r = 0; r < 4; ++r) {
      const int i = mi * 16 + lg * 4 + r;
      bab[i * 32 + c] = f2bf(acc[r]);
    }
  }
  // ---- pack action embedding ----
  if (t < 128) ba[(size_t)b * 1152 + 1024 + t] = f2bf(aemb[b * 128 + t]);
}

// ---------------------------------------------------------------------------
// Kernels 2-4: C = act(A_bf16[M,KDIM] @ W_bf16[1024,KDIM]^T + bias)
// 128x128 block tile, BK=32, 512 thr (8 waves, 4x2), wave tile 32x64.
// Reg-staged global->LDS with next-tile prefetch overlapping MFMA.
// LDS rows padded to 40 bf16 (80 B): 16B-granule-uniform for ds_read_b128.
// ---------------------------------------------------------------------------
template <int KDIM, bool ELU_ACT, bool OUT_BF16>
__global__ __launch_bounds__(512, 4) void gemm_kernel(
    const short* __restrict__ A, const short* __restrict__ W,
    const float* __restrict__ bias, void* __restrict__ outp) {
  static_assert(KDIM % 32 == 0, "");
  constexpr int LS = 40;
  constexpr int KT = KDIM / 32;
  __shared__ __align__(16) short As[128 * LS];
  __shared__ __align__(16) short Ws[128 * LS];

  const int t = threadIdx.x;
  const int lane = t & 63;
  const int w = t >> 6;          // 0..7
  const int wr = w >> 1;         // 0..3 (M)
  const int wc = w & 1;          // 0..1 (N)
  const int lr = lane & 15, lg = lane >> 4;
  const int kOff = lg * 8;

  const int tileN = blockIdx.x & 7;   // N/128 = 8
  const int tileM = blockIdx.x >> 3;

  const int sRow = t >> 2;            // 0..127: one 16B chunk per thread
  const int sCol = (t & 3) * 8;

  const short* aG = A + (size_t)(tileM * 128 + sRow) * KDIM + sCol;
  const short* wG = W + (size_t)(tileN * 128 + sRow) * KDIM + sCol;

  f32x4 acc[2][4] = {};
  int4 aR, wR;
  aR = *(const int4*)aG;
  wR = *(const int4*)wG;

  for (int kt = 0; kt < KT; ++kt) {
    *(int4*)&As[sRow * LS + sCol] = aR;
    *(int4*)&Ws[sRow * LS + sCol] = wR;
    __syncthreads();
    if (kt + 1 < KT) {  // prefetch next K-slab into regs; waited at next ds_write
      const int o = (kt + 1) * 32;
      aR = *(const int4*)(aG + o);
      wR = *(const int4*)(wG + o);
    }
    bf16x8 afr[2], bfr[4];
#pragma unroll
    for (int mi = 0; mi < 2; ++mi)
      afr[mi] = *(const bf16x8*)&As[(wr * 32 + mi * 16 + lr) * LS + kOff];
#pragma unroll
    for (int ni = 0; ni < 4; ++ni)
      bfr[ni] = *(const bf16x8*)&Ws[(wc * 64 + ni * 16 + lr) * LS + kOff];
#pragma unroll
    for (int mi = 0; mi < 2; ++mi)
#pragma unroll
      for (int ni = 0; ni < 4; ++ni)
        acc[mi][ni] = __builtin_amdgcn_mfma_f32_16x16x32_bf16(afr[mi], bfr[ni],
                                                              acc[mi][ni], 0, 0, 0);
    __syncthreads();
  }

  // epilogue: bias + optional ELU, store bf16 (ws) or f32 (d_out logits)
#pragma unroll
  for (int ni = 0; ni < 4; ++ni) {
    const int col = tileN * 128 + wc * 64 + ni * 16 + lr;
    const float bv = bias[col];
#pragma unroll
    for (int mi = 0; mi < 2; ++mi) {
#pragma unroll
      for (int r = 0; r < 4; ++r) {
        const int row = tileM * 128 + wr * 32 + mi * 16 + lg * 4 + r;
        float v = acc[mi][ni][r] + bv;
        if (ELU_ACT) v = (v > 0.f) ? v : expm1f(v);
        if (OUT_BF16) ((short*)outp)[(size_t)row * 1024 + col] = f2bf(v);
        else          ((float*)outp)[(size_t)row * 1024 + col] = v;
      }
    }
  }
}

// ---------------------------------------------------------------------------
// Kernel 5: gumbel softmax over contiguous 32-wide groups.
// pred = softmax((logits + g)/temp), g = -log(-log(u+eps)+eps)
// ---------------------------------------------------------------------------
__global__ __launch_bounds__(256) void gumbel_kernel(
    const float* __restrict__ logits, const float* __restrict__ gu,
    const float* __restrict__ temp, float* __restrict__ outp) {
  const float invt = 1.0f / temp[0];
  int idx = blockIdx.x * 256 + threadIdx.x;
  const int stride = 8192 * 256;
#pragma unroll
  for (int it = 0; it < 4; ++it, idx += stride) {
    const float l = logits[idx];
    const float u = gu[idx];
    const float g = -__logf(-__logf(u + 1e-20f) + 1e-20f);
    const float v = (l + g) * invt;
    float m = v;  // max over the 32-lane category group (xor masks stay in-group)
#pragma unroll
    for (int s = 1; s <= 16; s <<= 1) m = fmaxf(m, __shfl_xor(m, s));
    const float e = __expf(v - m);
    float ssum = e;
#pragma unroll
    for (int s = 1; s <= 16; s <<= 1) ssum += __shfl_xor(ssum, s);
    outp[idx] = e / ssum;
  }
}

// ---------------------------------------------------------------------------
extern "C" void kernel_launch(void* const* d_in, const int* in_sizes, int n_in,
                              void* d_out, int out_size, void* d_ws, size_t ws_size,
                              hipStream_t stream) {
  const float* lat  = (const float*)d_in[0];   // [8192,1024]
  const float* aemb = (const float*)d_in[1];   // [8192,128]
  const float* gum  = (const float*)d_in[2];   // [8192,32,32]
  const float* temp = (const float*)d_in[3];   // scalar
  const float* ipw  = (const float*)d_in[4];   // [96,32]
  const float* ipb  = (const float*)d_in[5];   // [96]
  const float* opw  = (const float*)d_in[6];   // [32,32]
  const float* opb  = (const float*)d_in[7];   // [32]
  const float* f1w  = (const float*)d_in[8];   // [1024,1152]
  const float* f1b  = (const float*)d_in[9];
  const float* f2w  = (const float*)d_in[10];  // [1024,1024]
  const float* f2b  = (const float*)d_in[11];
  const float* f3w  = (const float*)d_in[12];  // [1024,1024]
  const float* f3b  = (const float*)d_in[13];

  // workspace layout (bf16 buffers as short*), ~56.3 MB total
  char* ws = (char*)d_ws;
  short* w1 = (short*)(ws);                          // 1024*1152*2 = 2359296
  short* w2 = (short*)(ws + 2359296);                // 1024*1024*2 = 2097152
  short* w3 = (short*)(ws + 4456448);                // 2097152
  short* ba = (short*)(ws + 6553600);                // 8192*1152*2 = 18874368
  short* h1 = (short*)(ws + 25427968);               // 8192*1024*2 = 16777216
  short* h2 = (short*)(ws + 42205184);               // 16777216 (end 58982400)

  float* outp   = (float*)d_out;            // pred [8192*1024]
  float* logits = outp + 8388608;           // logits [8192*1024]

  cast_f2b<<<1152, 256, 0, stream>>>(f1w, w1, 1179648);
  cast_f2b<<<1024, 256, 0, stream>>>(f2w, w2, 1048576);
  cast_f2b<<<1024, 256, 0, stream>>>(f3w, w3, 1048576);

  attn_kernel<<<8192, 256, 0, stream>>>(lat, aemb, ipw, ipb, opw, opb, ba);

  gemm_kernel<1152, true,  true ><<<512, 512, 0, stream>>>(ba, w1, f1b, h1);
  gemm_kernel<1024, true,  true ><<<512, 512, 0, stream>>>(h1, w2, f2b, h2);
  gemm_kernel<1024, false, false><<<512, 512, 0, stream>>>(h2, w3, f3b, logits);

  gumbel_kernel<<<8192, 256, 0, stream>>>(logits, gum, temp, outp);
}